// Round 1
// baseline (573.532 us; speedup 1.0000x reference)
//
#include <hip/hip_runtime.h>

#define HH 128
#define GG 32
#define LL 3
#define BN_EPS 1e-5f

// ---- CSR build ----
__global__ __launch_bounds__(256) void k_deg(const int* __restrict__ ei, int* __restrict__ deg, int E) {
  int e = blockIdx.x * 256 + threadIdx.x;
  if (e < E) atomicAdd(&deg[ei[E + e]], 1);
}

__global__ __launch_bounds__(256) void k_gcnt(const int* __restrict__ batch, int* __restrict__ gcnt, int N) {
  int n = blockIdx.x * 256 + threadIdx.x;
  if (n < N) atomicAdd(&gcnt[batch[n]], 1);
}

// single-block exclusive scan (Hillis-Steele per 1024-chunk with running carry)
__global__ __launch_bounds__(1024) void k_scan(const int* __restrict__ in, int* __restrict__ out0,
                                               int* __restrict__ out1, int n) {
  __shared__ int sd[1024];
  __shared__ int carry_s;
  int tid = threadIdx.x;
  if (tid == 0) carry_s = 0;
  __syncthreads();
  for (int base = 0; base < n; base += 1024) {
    int v = (base + tid < n) ? in[base + tid] : 0;
    sd[tid] = v;
    __syncthreads();
    for (int off = 1; off < 1024; off <<= 1) {
      int t = (tid >= off) ? sd[tid - off] : 0;
      __syncthreads();
      sd[tid] += t;
      __syncthreads();
    }
    int excl = carry_s + sd[tid] - v;
    if (base + tid < n) {
      out0[base + tid] = excl;
      if (out1) out1[base + tid] = excl;
    }
    __syncthreads();
    if (tid == 1023) carry_s += sd[1023];
    __syncthreads();
  }
}

__global__ __launch_bounds__(256) void k_scatter(const int* __restrict__ ei, int* __restrict__ cursor,
                                                 int* __restrict__ csr_src, int E) {
  int e = blockIdx.x * 256 + threadIdx.x;
  if (e < E) {
    int d = ei[E + e];
    int p = atomicAdd(&cursor[d], 1);
    csr_src[p] = ei[e];
  }
}

// ---- mean aggregation: one wave (64 lanes x float2) per node ----
__global__ __launch_bounds__(256) void k_aggregate(const int* __restrict__ csr_off, const int* __restrict__ deg,
                                                   const int* __restrict__ csr_src, const float* __restrict__ hin,
                                                   float* __restrict__ agg, int N) {
  int wid = (blockIdx.x * 256 + threadIdx.x) >> 6;
  int lane = threadIdx.x & 63;
  if (wid >= N) return;
  int off = csr_off[wid];
  int d = deg[wid];
  int col = lane * 2;
  float ax = 0.f, ay = 0.f;
  int j = 0;
  for (; j + 2 <= d; j += 2) {
    int s0 = csr_src[off + j];
    int s1 = csr_src[off + j + 1];
    float2 v0 = *(const float2*)&hin[(size_t)s0 * HH + col];
    float2 v1 = *(const float2*)&hin[(size_t)s1 * HH + col];
    ax += v0.x; ay += v0.y;
    ax += v1.x; ay += v1.y;
  }
  if (j < d) {
    int s0 = csr_src[off + j];
    float2 v0 = *(const float2*)&hin[(size_t)s0 * HH + col];
    ax += v0.x; ay += v0.y;
  }
  float inv = d > 0 ? 1.0f / (float)d : 0.0f;
  float2 o;
  o.x = ax * inv;
  o.y = ay * inv;
  *(float2*)&agg[(size_t)wid * HH + col] = o;
}

// ---- fused dual GEMM + bias + BN(eval) + ReLU ----
// tile: 64 rows x 128 cols, K = 256 ([agg | hin] vs [wl ; wr]), 256 threads, 8x4 micro-tile
__global__ __launch_bounds__(256) void k_gemm(const float* __restrict__ agg, const float* __restrict__ hin,
                                              const float* __restrict__ wlp, const float* __restrict__ wrp,
                                              const float* __restrict__ bias, const float* __restrict__ gma,
                                              const float* __restrict__ bta, const float* __restrict__ mea,
                                              const float* __restrict__ var, float* __restrict__ hout, int N) {
  __shared__ float As[32][68];   // [k][row], padded to 68 for aligned b128 + fewer write conflicts
  __shared__ float Ws[32][HH];   // [k][col]
  int tid = threadIdx.x;
  int n0 = blockIdx.x * 64;
  int tc = tid & 31, tr = tid >> 5;
  int c0 = tc * 4, r0 = tr * 8;
  float acc[8][4] = {};
  for (int k0 = 0; k0 < 2 * HH; k0 += 32) {
    const float* Asrc = (k0 < HH) ? agg : hin;
    const float* Wsrc = (k0 < HH) ? wlp : wrp;
    int kk0 = k0 & (HH - 1);
    {  // stage A chunk: 64 rows x 32 k
      int row = tid >> 2;
      int kq = (tid & 3) * 8;
      int n = n0 + row;
      float4 v0, v1;
      if (n < N) {
        const float* p = Asrc + (size_t)n * HH + kk0 + kq;
        v0 = *(const float4*)p;
        v1 = *(const float4*)(p + 4);
      } else {
        v0 = make_float4(0.f, 0.f, 0.f, 0.f);
        v1 = v0;
      }
      As[kq + 0][row] = v0.x; As[kq + 1][row] = v0.y;
      As[kq + 2][row] = v0.z; As[kq + 3][row] = v0.w;
      As[kq + 4][row] = v1.x; As[kq + 5][row] = v1.y;
      As[kq + 6][row] = v1.z; As[kq + 7][row] = v1.w;
    }
    {  // stage W chunk: 32 k x 128 cols (contiguous)
      const float4* srcp = (const float4*)(Wsrc + (size_t)kk0 * HH);
      float4* dstp = (float4*)&Ws[0][0];
#pragma unroll
      for (int jj = 0; jj < 4; jj++) dstp[tid + jj * 256] = srcp[tid + jj * 256];
    }
    __syncthreads();
#pragma unroll
    for (int k = 0; k < 32; k++) {
      float a0[8], w0[4];
      *(float4*)&a0[0] = *(const float4*)&As[k][r0];
      *(float4*)&a0[4] = *(const float4*)&As[k][r0 + 4];
      *(float4*)&w0[0] = *(const float4*)&Ws[k][c0];
#pragma unroll
      for (int r = 0; r < 8; r++)
#pragma unroll
        for (int c = 0; c < 4; c++) acc[r][c] = fmaf(a0[r], w0[c], acc[r][c]);
    }
    __syncthreads();
  }
  // epilogue: bias + BN + ReLU folded to scale/shift per column
  float sc[4], sh[4];
#pragma unroll
  for (int c = 0; c < 4; c++) {
    float g = gma[c0 + c], vv = var[c0 + c], m = mea[c0 + c], bt = bta[c0 + c], bb = bias[c0 + c];
    float s = g * rsqrtf(vv + BN_EPS);
    sc[c] = s;
    sh[c] = (bb - m) * s + bt;
  }
#pragma unroll
  for (int r = 0; r < 8; r++) {
    int n = n0 + r0 + r;
    if (n < N) {
      float4 o;
      o.x = fmaxf(acc[r][0] * sc[0] + sh[0], 0.f);
      o.y = fmaxf(acc[r][1] * sc[1] + sh[1], 0.f);
      o.z = fmaxf(acc[r][2] * sc[2] + sh[2], 0.f);
      o.w = fmaxf(acc[r][3] * sc[3] + sh[3], 0.f);
      *(float4*)&hout[(size_t)n * HH + c0] = o;
    }
  }
}

// ---- graph pooling (batch sorted -> contiguous row ranges) + concat global feats ----
__global__ __launch_bounds__(128) void k_pool(const float* __restrict__ h, const int* __restrict__ goff,
                                              const int* __restrict__ gcnt, const float* __restrict__ gfeat,
                                              float* __restrict__ pz) {
  int g = blockIdx.x;
  int t = threadIdx.x;
  int off = goff[g], cnt = gcnt[g];
  float s = 0.f;
  for (int j = 0; j < cnt; j++) s += h[(size_t)(off + j) * HH + t];
  float inv = cnt > 0 ? 1.0f / (float)cnt : 0.f;
  pz[(size_t)g * (HH + GG) + t] = s * inv;
  if (t < GG) pz[(size_t)g * (HH + GG) + HH + t] = gfeat[g * GG + t];
}

// ---- final MLP: one wave per graph ----
__global__ __launch_bounds__(64) void k_mlp(const float* __restrict__ pz, const float* __restrict__ w1,
                                            const float* __restrict__ b1, const float* __restrict__ w2,
                                            const float* __restrict__ b2, float* __restrict__ out) {
  int g = blockIdx.x;
  int t = threadIdx.x;
  const float* z = pz + (size_t)g * (HH + GG);
  float acc = b1[t];
  for (int k = 0; k < HH + GG; k++) acc = fmaf(z[k], w1[k * 64 + t], acc);
  acc = fmaxf(acc, 0.f);
  float v = acc * w2[t];
#pragma unroll
  for (int o = 32; o > 0; o >>= 1) v += __shfl_down(v, o);
  if (t == 0) out[g] = v + b2[0];
}

extern "C" void kernel_launch(void* const* d_in, const int* in_sizes, int n_in,
                              void* d_out, int out_size, void* d_ws, size_t ws_size,
                              hipStream_t stream) {
  const float* x = (const float*)d_in[0];
  const int* ei = (const int*)d_in[1];
  const int* batch = (const int*)d_in[2];
  const float* gfeat = (const float*)d_in[3];
  const float* wl = (const float*)d_in[4];
  const float* wr = (const float*)d_in[5];
  const float* bias = (const float*)d_in[6];
  const float* gma = (const float*)d_in[7];
  const float* bta = (const float*)d_in[8];
  const float* mea = (const float*)d_in[9];
  const float* var = (const float*)d_in[10];
  const float* w1 = (const float*)d_in[11];
  const float* b1 = (const float*)d_in[12];
  const float* w2 = (const float*)d_in[13];
  const float* b2 = (const float*)d_in[14];
  int N = in_sizes[0] / HH;
  int E = in_sizes[1] / 2;
  int B = in_sizes[3] / GG;
  float* out = (float*)d_out;
  (void)n_in; (void)out_size; (void)ws_size;

  char* base = (char*)d_ws;
  size_t off = 0;
  auto alloc = [&](size_t bytes) -> void* {
    void* p = base + off;
    off = (off + bytes + 255) & ~(size_t)255;
    return p;
  };
  int* deg = (int*)alloc((size_t)N * 4);
  int* csr_off = (int*)alloc((size_t)N * 4);
  int* cursor = (int*)alloc((size_t)N * 4);
  int* gcnt = (int*)alloc((size_t)B * 4);
  int* goff = (int*)alloc((size_t)B * 4);
  int* csr_src = (int*)alloc((size_t)E * 4);
  float* agg = (float*)alloc((size_t)N * HH * 4);
  float* hbuf = (float*)alloc((size_t)N * HH * 4);
  float* pz = (float*)alloc((size_t)B * (HH + GG) * 4);

  hipMemsetAsync(deg, 0, (size_t)N * 4, stream);
  hipMemsetAsync(gcnt, 0, (size_t)B * 4, stream);
  k_deg<<<(E + 255) / 256, 256, 0, stream>>>(ei, deg, E);
  k_gcnt<<<(N + 255) / 256, 256, 0, stream>>>(batch, gcnt, N);
  k_scan<<<1, 1024, 0, stream>>>(deg, csr_off, cursor, N);
  k_scan<<<1, 1024, 0, stream>>>(gcnt, goff, (int*)nullptr, B);
  k_scatter<<<(E + 255) / 256, 256, 0, stream>>>(ei, cursor, csr_src, E);

  for (int l = 0; l < LL; l++) {
    const float* hin = (l == 0) ? x : hbuf;
    k_aggregate<<<(N + 3) / 4, 256, 0, stream>>>(csr_off, deg, csr_src, hin, agg, N);
    k_gemm<<<(N + 63) / 64, 256, 0, stream>>>(agg, hin, wl + (size_t)l * HH * HH, wr + (size_t)l * HH * HH,
                                              bias + (size_t)l * HH, gma + (size_t)l * HH, bta + (size_t)l * HH,
                                              mea + (size_t)l * HH, var + (size_t)l * HH, hbuf, N);
  }
  k_pool<<<B, 128, 0, stream>>>(hbuf, goff, gcnt, gfeat, pz);
  k_mlp<<<B, 64, 0, stream>>>(pz, w1, b1, w2, b2, out);
}

// Round 2
// 479.850 us; speedup vs baseline: 1.1952x; 1.1952x over previous
//
#include <hip/hip_runtime.h>

#define HH 128
#define GG 32
#define LL 3
#define BN_EPS 1e-5f

// ---- CSR build ----
__global__ __launch_bounds__(256) void k_deg(const int* __restrict__ ei, int* __restrict__ deg, int E) {
  int e = blockIdx.x * 256 + threadIdx.x;
  if (e < E) atomicAdd(&deg[ei[E + e]], 1);
}

__global__ __launch_bounds__(256) void k_gcnt(const int* __restrict__ batch, int* __restrict__ gcnt, int N) {
  int n = blockIdx.x * 256 + threadIdx.x;
  if (n < N) atomicAdd(&gcnt[batch[n]], 1);
}

// ---- parallel 3-phase exclusive scan ----
__global__ __launch_bounds__(1024) void k_scan_blk(const int* __restrict__ in, int* __restrict__ out,
                                                   int* __restrict__ bsum, int n) {
  __shared__ int sd[1024];
  int tid = threadIdx.x;
  int i = blockIdx.x * 1024 + tid;
  int v = (i < n) ? in[i] : 0;
  sd[tid] = v;
  __syncthreads();
  for (int off = 1; off < 1024; off <<= 1) {
    int t = (tid >= off) ? sd[tid - off] : 0;
    __syncthreads();
    sd[tid] += t;
    __syncthreads();
  }
  if (i < n) out[i] = sd[tid] - v;  // exclusive within block
  if (tid == 1023) bsum[blockIdx.x] = sd[1023];
}

__global__ __launch_bounds__(1024) void k_scan_top(int* __restrict__ bsum, int nb) {
  __shared__ int sd[1024];
  int tid = threadIdx.x;
  int v = (tid < nb) ? bsum[tid] : 0;
  sd[tid] = v;
  __syncthreads();
  for (int off = 1; off < 1024; off <<= 1) {
    int t = (tid >= off) ? sd[tid - off] : 0;
    __syncthreads();
    sd[tid] += t;
    __syncthreads();
  }
  if (tid < nb) bsum[tid] = sd[tid] - v;  // exclusive block offsets
}

__global__ __launch_bounds__(1024) void k_scan_add(int* __restrict__ out0, int* __restrict__ out1,
                                                   const int* __restrict__ bsum, int n) {
  int i = blockIdx.x * 1024 + threadIdx.x;
  if (i < n) {
    int v = out0[i] + bsum[blockIdx.x];
    out0[i] = v;
    if (out1) out1[i] = v;
  }
}

__global__ __launch_bounds__(256) void k_scatter(const int* __restrict__ ei, int* __restrict__ cursor,
                                                 int* __restrict__ csr_src, int E) {
  int e = blockIdx.x * 256 + threadIdx.x;
  if (e < E) {
    int d = ei[E + e];
    int p = atomicAdd(&cursor[d], 1);
    csr_src[p] = ei[e];
  }
}

// ---- mean aggregation: one wave per node, 2 rows/iter (lanes split 32/32, float4 each), 2x unroll ----
__global__ __launch_bounds__(256) void k_aggregate(const int* __restrict__ csr_off, const int* __restrict__ deg,
                                                   const int* __restrict__ csr_src, const float* __restrict__ hin,
                                                   float* __restrict__ agg, int N) {
  int wid = (blockIdx.x * 256 + threadIdx.x) >> 6;
  int lane = threadIdx.x & 63;
  if (wid >= N) return;
  int off = csr_off[wid];
  int d = deg[wid];
  int half = lane >> 5;
  int col = (lane & 31) * 4;
  float ax = 0.f, ay = 0.f, az = 0.f, aw = 0.f;
  int j = 0;
  for (; j + 4 <= d; j += 4) {  // 4 rows in flight
    int sA = csr_src[off + j + half];
    int sB = csr_src[off + j + 2 + half];
    float4 vA = *(const float4*)&hin[(size_t)sA * HH + col];
    float4 vB = *(const float4*)&hin[(size_t)sB * HH + col];
    ax += vA.x; ay += vA.y; az += vA.z; aw += vA.w;
    ax += vB.x; ay += vB.y; az += vB.z; aw += vB.w;
  }
  for (; j + 2 <= d; j += 2) {
    int s = csr_src[off + j + half];
    float4 v = *(const float4*)&hin[(size_t)s * HH + col];
    ax += v.x; ay += v.y; az += v.z; aw += v.w;
  }
  if (j < d && half == 0) {
    int s = csr_src[off + j];
    float4 v = *(const float4*)&hin[(size_t)s * HH + col];
    ax += v.x; ay += v.y; az += v.z; aw += v.w;
  }
  ax += __shfl_down(ax, 32);
  ay += __shfl_down(ay, 32);
  az += __shfl_down(az, 32);
  aw += __shfl_down(aw, 32);
  if (half == 0) {
    float inv = d > 0 ? 1.0f / (float)d : 0.0f;
    float4 o;
    o.x = ax * inv; o.y = ay * inv; o.z = az * inv; o.w = aw * inv;
    *(float4*)&agg[(size_t)wid * HH + col] = o;
  }
}

// ---- fused dual GEMM + bias + BN(eval) + ReLU ----
// tile: 64 rows x 128 cols, K = 256 ([agg | hin] vs [wl ; wr]), 256 threads, 8x4 micro-tile
__global__ __launch_bounds__(256) void k_gemm(const float* __restrict__ agg, const float* __restrict__ hin,
                                              const float* __restrict__ wlp, const float* __restrict__ wrp,
                                              const float* __restrict__ bias, const float* __restrict__ gma,
                                              const float* __restrict__ bta, const float* __restrict__ mea,
                                              const float* __restrict__ var, float* __restrict__ hout, int N) {
  __shared__ float As[32][68];   // [k][row]
  __shared__ float Ws[32][HH];   // [k][col]
  int tid = threadIdx.x;
  int n0 = blockIdx.x * 64;
  int tc = tid & 31, tr = tid >> 5;
  int c0 = tc * 4, r0 = tr * 8;
  float acc[8][4] = {};
  for (int k0 = 0; k0 < 2 * HH; k0 += 32) {
    const float* Asrc = (k0 < HH) ? agg : hin;
    const float* Wsrc = (k0 < HH) ? wlp : wrp;
    int kk0 = k0 & (HH - 1);
    {  // stage A chunk: 64 rows x 32 k
      int row = tid >> 2;
      int kq = (tid & 3) * 8;
      int n = n0 + row;
      float4 v0, v1;
      if (n < N) {
        const float* p = Asrc + (size_t)n * HH + kk0 + kq;
        v0 = *(const float4*)p;
        v1 = *(const float4*)(p + 4);
      } else {
        v0 = make_float4(0.f, 0.f, 0.f, 0.f);
        v1 = v0;
      }
      As[kq + 0][row] = v0.x; As[kq + 1][row] = v0.y;
      As[kq + 2][row] = v0.z; As[kq + 3][row] = v0.w;
      As[kq + 4][row] = v1.x; As[kq + 5][row] = v1.y;
      As[kq + 6][row] = v1.z; As[kq + 7][row] = v1.w;
    }
    {  // stage W chunk: 32 k x 128 cols (contiguous)
      const float4* srcp = (const float4*)(Wsrc + (size_t)kk0 * HH);
      float4* dstp = (float4*)&Ws[0][0];
#pragma unroll
      for (int jj = 0; jj < 4; jj++) dstp[tid + jj * 256] = srcp[tid + jj * 256];
    }
    __syncthreads();
#pragma unroll
    for (int k = 0; k < 32; k++) {
      float a0[8], w0[4];
      *(float4*)&a0[0] = *(const float4*)&As[k][r0];
      *(float4*)&a0[4] = *(const float4*)&As[k][r0 + 4];
      *(float4*)&w0[0] = *(const float4*)&Ws[k][c0];
#pragma unroll
      for (int r = 0; r < 8; r++)
#pragma unroll
        for (int c = 0; c < 4; c++) acc[r][c] = fmaf(a0[r], w0[c], acc[r][c]);
    }
    __syncthreads();
  }
  // epilogue: bias + BN + ReLU folded to scale/shift per column
  float sc[4], sh[4];
#pragma unroll
  for (int c = 0; c < 4; c++) {
    float g = gma[c0 + c], vv = var[c0 + c], m = mea[c0 + c], bt = bta[c0 + c], bb = bias[c0 + c];
    float s = g * rsqrtf(vv + BN_EPS);
    sc[c] = s;
    sh[c] = (bb - m) * s + bt;
  }
#pragma unroll
  for (int r = 0; r < 8; r++) {
    int n = n0 + r0 + r;
    if (n < N) {
      float4 o;
      o.x = fmaxf(acc[r][0] * sc[0] + sh[0], 0.f);
      o.y = fmaxf(acc[r][1] * sc[1] + sh[1], 0.f);
      o.z = fmaxf(acc[r][2] * sc[2] + sh[2], 0.f);
      o.w = fmaxf(acc[r][3] * sc[3] + sh[3], 0.f);
      *(float4*)&hout[(size_t)n * HH + c0] = o;
    }
  }
}

// ---- graph pooling (batch sorted -> contiguous row ranges) + concat global feats ----
__global__ __launch_bounds__(128) void k_pool(const float* __restrict__ h, const int* __restrict__ goff,
                                              const int* __restrict__ gcnt, const float* __restrict__ gfeat,
                                              float* __restrict__ pz) {
  int g = blockIdx.x;
  int t = threadIdx.x;
  int off = goff[g], cnt = gcnt[g];
  float s = 0.f;
  for (int j = 0; j < cnt; j++) s += h[(size_t)(off + j) * HH + t];
  float inv = cnt > 0 ? 1.0f / (float)cnt : 0.f;
  pz[(size_t)g * (HH + GG) + t] = s * inv;
  if (t < GG) pz[(size_t)g * (HH + GG) + HH + t] = gfeat[g * GG + t];
}

// ---- final MLP: one wave per graph ----
__global__ __launch_bounds__(64) void k_mlp(const float* __restrict__ pz, const float* __restrict__ w1,
                                            const float* __restrict__ b1, const float* __restrict__ w2,
                                            const float* __restrict__ b2, float* __restrict__ out) {
  int g = blockIdx.x;
  int t = threadIdx.x;
  const float* z = pz + (size_t)g * (HH + GG);
  float acc = b1[t];
  for (int k = 0; k < HH + GG; k++) acc = fmaf(z[k], w1[k * 64 + t], acc);
  acc = fmaxf(acc, 0.f);
  float v = acc * w2[t];
#pragma unroll
  for (int o = 32; o > 0; o >>= 1) v += __shfl_down(v, o);
  if (t == 0) out[g] = v + b2[0];
}

extern "C" void kernel_launch(void* const* d_in, const int* in_sizes, int n_in,
                              void* d_out, int out_size, void* d_ws, size_t ws_size,
                              hipStream_t stream) {
  const float* x = (const float*)d_in[0];
  const int* ei = (const int*)d_in[1];
  const int* batch = (const int*)d_in[2];
  const float* gfeat = (const float*)d_in[3];
  const float* wl = (const float*)d_in[4];
  const float* wr = (const float*)d_in[5];
  const float* bias = (const float*)d_in[6];
  const float* gma = (const float*)d_in[7];
  const float* bta = (const float*)d_in[8];
  const float* mea = (const float*)d_in[9];
  const float* var = (const float*)d_in[10];
  const float* w1 = (const float*)d_in[11];
  const float* b1 = (const float*)d_in[12];
  const float* w2 = (const float*)d_in[13];
  const float* b2 = (const float*)d_in[14];
  int N = in_sizes[0] / HH;
  int E = in_sizes[1] / 2;
  int B = in_sizes[3] / GG;
  float* out = (float*)d_out;
  (void)n_in; (void)out_size; (void)ws_size;

  char* base = (char*)d_ws;
  size_t off = 0;
  auto alloc = [&](size_t bytes) -> void* {
    void* p = base + off;
    off = (off + bytes + 255) & ~(size_t)255;
    return p;
  };
  int* deg = (int*)alloc((size_t)N * 4);
  int* csr_off = (int*)alloc((size_t)N * 4);
  int* cursor = (int*)alloc((size_t)N * 4);
  int* gcnt = (int*)alloc((size_t)B * 4);
  int* goff = (int*)alloc((size_t)B * 4);
  int* csr_src = (int*)alloc((size_t)E * 4);
  float* agg = (float*)alloc((size_t)N * HH * 4);
  float* hbuf = (float*)alloc((size_t)N * HH * 4);
  float* pz = (float*)alloc((size_t)B * (HH + GG) * 4);
  int* bsumN = (int*)alloc(1024 * 4);
  int* bsumB = (int*)alloc(1024 * 4);

  hipMemsetAsync(deg, 0, (size_t)N * 4, stream);
  hipMemsetAsync(gcnt, 0, (size_t)B * 4, stream);
  k_deg<<<(E + 255) / 256, 256, 0, stream>>>(ei, deg, E);
  k_gcnt<<<(N + 255) / 256, 256, 0, stream>>>(batch, gcnt, N);

  int nbN = (N + 1023) / 1024;
  k_scan_blk<<<nbN, 1024, 0, stream>>>(deg, csr_off, bsumN, N);
  k_scan_top<<<1, 1024, 0, stream>>>(bsumN, nbN);
  k_scan_add<<<nbN, 1024, 0, stream>>>(csr_off, cursor, bsumN, N);

  int nbB = (B + 1023) / 1024;
  k_scan_blk<<<nbB, 1024, 0, stream>>>(gcnt, goff, bsumB, B);
  k_scan_top<<<1, 1024, 0, stream>>>(bsumB, nbB);
  k_scan_add<<<nbB, 1024, 0, stream>>>(goff, (int*)nullptr, bsumB, B);

  k_scatter<<<(E + 255) / 256, 256, 0, stream>>>(ei, cursor, csr_src, E);

  for (int l = 0; l < LL; l++) {
    const float* hin = (l == 0) ? x : hbuf;
    k_aggregate<<<(N + 3) / 4, 256, 0, stream>>>(csr_off, deg, csr_src, hin, agg, N);
    k_gemm<<<(N + 63) / 64, 256, 0, stream>>>(agg, hin, wl + (size_t)l * HH * HH, wr + (size_t)l * HH * HH,
                                              bias + (size_t)l * HH, gma + (size_t)l * HH, bta + (size_t)l * HH,
                                              mea + (size_t)l * HH, var + (size_t)l * HH, hbuf, N);
  }
  k_pool<<<B, 128, 0, stream>>>(hbuf, goff, gcnt, gfeat, pz);
  k_mlp<<<B, 64, 0, stream>>>(pz, w1, b1, w2, b2, out);
}